// Round 7
// baseline (549.608 us; speedup 1.0000x reference)
//
#include <hip/hip_runtime.h>
#include <hip/hip_bf16.h>

typedef __hip_bfloat16 bf16;
typedef unsigned int u32;
typedef __attribute__((ext_vector_type(8))) short bf16x8;
typedef __attribute__((ext_vector_type(4))) float f32x4;

#define HWSZ 65536u   // 256*256

__device__ __forceinline__ float b2f_lo(u32 w){ return __uint_as_float(w << 16); }
__device__ __forceinline__ float b2f_hi(u32 w){ return __uint_as_float(w & 0xffff0000u); }
__device__ __forceinline__ float b2f(bf16 v){ return __bfloat162float(v); }
__device__ __forceinline__ bf16 f2b(float v){ return __float2bfloat16(v); }

__device__ __forceinline__ u32 f2bbits(float f){
  u32 x = __float_as_uint(f);
  return ((x + 0x7fffu + ((x >> 16) & 1u)) >> 16) & 0xffffu;  // RNE
}

__device__ __forceinline__ void unpack8(uint4 v, float* f){
  f[0]=b2f_lo(v.x); f[1]=b2f_hi(v.x);
  f[2]=b2f_lo(v.y); f[3]=b2f_hi(v.y);
  f[4]=b2f_lo(v.z); f[5]=b2f_hi(v.z);
  f[6]=b2f_lo(v.w); f[7]=b2f_hi(v.w);
}

union ABu { u32 u[4]; bf16x8 v; uint4 q; };

// XOR-swizzled xs index: c8-aware so the 8 c8 groups occupy distinct bank slots.
__device__ __forceinline__ int xsw(int c8, int px){
  return c8 * 192 + ((px & ~7) | ((px ^ c8) & 7));
}

// ---------------- K12 (fused, v2): pointwise qkv (MFMA) + 3x3 depthwise + tokenize
// 512 threads (8 waves), block = (b, yt 16-row band, xt 8-col strip).
// Region px = 18 rows x 10 cols = 180, padded to 192 (12 MFMA n-tiles).
// xs: x bf16 [c8=8][px=192] 16B units, c8-XOR swizzle. qs: [px=192][och 64+4].
__global__ __launch_bounds__(512, 6) void k12_fused(
    const float* __restrict__ x, const float* __restrict__ wq,
    const float* __restrict__ wdw, bf16* __restrict__ tok){
  __shared__ uint4 xs[8 * 192];              // 24.0 KB
  __shared__ unsigned short qs[192 * 68];    // 25.5 KB
  int t = threadIdx.x;
  int lane = t & 63, w = t >> 6;             // 8 waves
  int r16 = lane & 15, g4 = lane >> 4;

  u32 n = blockIdx.x;
  u32 bid = (n & 7u) * 1024u + (n >> 3);     // XCD swizzle (8192 = 8*1024, bijective)
  u32 xt = bid & 31u, yt = (bid >> 5) & 15u, b = bid >> 9;
  int y0 = (int)yt * 16, x0 = (int)xt * 8;

  const float* xb = x + (size_t)b * 64 * HWSZ;

  // ---- stage x: 576 units = (c8, rr in [0,18), jq in [0,4)); unit = 2 ch x 10 cols
  for (int u = t; u < 576; u += 512){
    int jq = u & 3, rr = (u >> 2) % 18, c8 = u / 72;
    int yy = y0 - 1 + rr;
    float va[2][10];
    if ((u32)yy < 256u){
      #pragma unroll
      for (int jc = 0; jc < 2; jc++){
        const float* p = xb + (size_t)(c8 * 8 + jq * 2 + jc) * HWSZ + ((size_t)yy << 8);
        float4 A  = *(const float4*)(p + x0);        // 16B-aligned (x0 % 8 == 0)
        float4 Bq = *(const float4*)(p + x0 + 4);
        va[jc][0] = (x0 > 0) ? p[x0 - 1] : 0.f;
        va[jc][1] = A.x;  va[jc][2] = A.y;  va[jc][3] = A.z;  va[jc][4] = A.w;
        va[jc][5] = Bq.x; va[jc][6] = Bq.y; va[jc][7] = Bq.z; va[jc][8] = Bq.w;
        va[jc][9] = (x0 + 8 < 256) ? p[x0 + 8] : 0.f;
      }
    } else {
      #pragma unroll
      for (int jc = 0; jc < 2; jc++)
        #pragma unroll
        for (int e = 0; e < 10; e++) va[jc][e] = 0.f;
    }
    #pragma unroll
    for (int e = 0; e < 10; e++){
      u32 wv = f2bbits(va[0][e]) | (f2bbits(va[1][e]) << 16);
      ((u32*)&xs[xsw(c8, rr * 10 + e)])[jq] = wv;
    }
  }
  if (t < 96){                                        // zero-pad px 180..191
    int c8 = t / 12, px = 180 + (t % 12);
    xs[xsw(c8, px)] = make_uint4(0u, 0u, 0u, 0u);
  }

  int cth = lane, rp = w;                             // dwconv: (ch, row-pair)
  int ot = w & 3, nh = w >> 2;                        // MFMA: (och-tile, px-half)
  u32 win = (yt >> 1) * 8u + (xt >> 2);

  for (int g = 0; g < 3; g++){
    __syncthreads();                                  // xs ready / qs free
    // ---- pointwise MFMA: wave (ot, nh) -> 6 n-tiles of och-tile ot
    bf16x8 af[2];
    {
      int och = g * 64 + ot * 16 + r16;
      #pragma unroll
      for (int kt = 0; kt < 2; kt++){
        const float* wr = wq + och * 64 + kt * 32 + g4 * 8;
        ABu pk;
        #pragma unroll
        for (int j = 0; j < 4; j++)
          pk.u[j] = f2bbits(wr[2 * j]) | (f2bbits(wr[2 * j + 1]) << 16);
        af[kt] = pk.v;
      }
    }
    #pragma unroll
    for (int nt2 = 0; nt2 < 6; nt2++){
      int nt = nh * 6 + nt2;
      f32x4 acc = (f32x4){0.f, 0.f, 0.f, 0.f};
      #pragma unroll
      for (int kt = 0; kt < 2; kt++){
        uint4 uq = xs[xsw(kt * 4 + g4, nt * 16 + r16)];
        acc = __builtin_amdgcn_mfma_f32_16x16x32_bf16(
            af[kt], *reinterpret_cast<bf16x8*>(&uq), acc, 0, 0, 0);
      }
      int px = nt * 16 + r16;
      u32 lo = f2bbits(acc[0]) | (f2bbits(acc[1]) << 16);
      u32 hi = f2bbits(acc[2]) | (f2bbits(acc[3]) << 16);
      *(uint2*)&qs[px * 68 + ot * 16 + g4 * 4] = make_uint2(lo, hi);
    }
    __syncthreads();                                  // qs ready

    // ---- depthwise 3x3 + tokenized store: thread = (cth, rows rp*2, rp*2+1)
    const float* wg = wdw + ((size_t)g * 64 + cth) * 9;
    float d0=wg[0],d1=wg[1],d2=wg[2],d3=wg[3],d4=wg[4],d5=wg[5],d6=wg[6],d7=wg[7],d8=wg[8];
    float rbf[4][10];
    #define QLD(s, R) do{ _Pragma("unroll") for (int _cr = 0; _cr < 10; _cr++) \
      rbf[s][_cr] = __uint_as_float(((u32)qs[((R) * 10 + _cr) * 68 + cth]) << 16); }while(0)
    QLD(0, rp * 2 + 0);
    QLD(1, rp * 2 + 1);
    QLD(2, rp * 2 + 2);
    QLD(3, rp * 2 + 3);
    #undef QLD
    #pragma unroll
    for (int rr2 = 0; rr2 < 2; rr2++){
      int r = rp * 2 + rr2;
      int h = (int)(yt & 1u) * 4 + (r >> 2);
      bf16* op = tok + (((((size_t)g * 16 + b) * 8 + h) * 64 + win) * 8192)
               + (size_t)(r & 3) * 2048 + (size_t)(xt & 3u) * 512 + cth;
      #pragma unroll
      for (int co = 0; co < 8; co++){
        float o = rbf[rr2][co]    * d0 + rbf[rr2][co + 1]    * d1 + rbf[rr2][co + 2]    * d2
                + rbf[rr2 + 1][co]* d3 + rbf[rr2 + 1][co + 1]* d4 + rbf[rr2 + 1][co + 2]* d5
                + rbf[rr2 + 2][co]* d6 + rbf[rr2 + 2][co + 1]* d7 + rbf[rr2 + 2][co + 2]* d8;
        op[co * 64] = f2b(o);
      }
    }
  }
}

// ---------------- K3 (MFMA): sim partials over d-quarter -> sim4[part][b][h][64][64]
__global__ __launch_bounds__(256) void k3_sim(
    const bf16* __restrict__ tok, float* __restrict__ sim4){
  __shared__ short qs[64 * 72];
  __shared__ short ks[64 * 72];
  int t = threadIdx.x;
  int lane = t & 63, w = t >> 6;
  int r16 = lane & 15, g4 = lane >> 4;
  u32 bid = blockIdx.x;
  u32 part = bid & 3u, h = (bid >> 2) & 7u, b = bid >> 5;
  const bf16* qb = tok + ((size_t)(((0 * 16 + b) * 8 + h) * 64)) * 8192 + part * 2048;
  const bf16* kb = tok + ((size_t)(((1 * 16 + b) * 8 + h) * 64)) * 8192 + part * 2048;

  int stok = t >> 2, soct = t & 3;

  f32x4 acc[4];
  #pragma unroll
  for (int jt = 0; jt < 4; jt++) acc[jt] = (f32x4){0.f,0.f,0.f,0.f};

  for (int s = 0; s < 32; s++){
    int d0 = s * 64;
    __syncthreads();
    {
      uint4 q0 = *(const uint4*)(qb + (size_t)stok * 8192 + d0 + soct * 8);
      uint4 q1 = *(const uint4*)(qb + (size_t)stok * 8192 + d0 + soct * 8 + 32);
      uint4 k0 = *(const uint4*)(kb + (size_t)stok * 8192 + d0 + soct * 8);
      uint4 k1 = *(const uint4*)(kb + (size_t)stok * 8192 + d0 + soct * 8 + 32);
      *(uint4*)&qs[stok * 72 + soct * 8]      = q0;
      *(uint4*)&qs[stok * 72 + soct * 8 + 32] = q1;
      *(uint4*)&ks[stok * 72 + soct * 8]      = k0;
      *(uint4*)&ks[stok * 72 + soct * 8 + 32] = k1;
    }
    __syncthreads();
    #pragma unroll
    for (int kt = 0; kt < 2; kt++){
      bf16x8 a = *(const bf16x8*)&qs[(w * 16 + r16) * 72 + kt * 32 + g4 * 8];
      #pragma unroll
      for (int jt = 0; jt < 4; jt++){
        bf16x8 bb = *(const bf16x8*)&ks[(jt * 16 + r16) * 72 + kt * 32 + g4 * 8];
        acc[jt] = __builtin_amdgcn_mfma_f32_16x16x32_bf16(a, bb, acc[jt], 0, 0, 0);
      }
    }
  }

  float* sp = sim4 + ((((size_t)part * 16 + b) * 8 + h) * 64) * 64;
  #pragma unroll
  for (int jt = 0; jt < 4; jt++)
    #pragma unroll
    for (int r = 0; r < 4; r++)
      sp[(w * 16 + g4 * 4 + r) * 64 + jt * 16 + r16] = acc[jt][r];
}

// ---------------- K4: combine partials, scale, +pos_emb, softmax
__global__ __launch_bounds__(64) void k4_softmax(
    const float* __restrict__ sim4, const float* __restrict__ pos, float* __restrict__ attn){
  int j = threadIdx.x;
  u32 bid = blockIdx.x;
  u32 i = bid & 63u, h = (bid >> 6) & 7u, b = bid >> 9;
  size_t o = (((size_t)b * 8 + h) * 64 + i) * 64 + j;
  const size_t pstride = (size_t)16 * 8 * 64 * 64;
  float s = sim4[o] + sim4[o + pstride] + sim4[o + 2 * pstride] + sim4[o + 3 * pstride];
  s = s * 0.011048543456039806f + pos[(((size_t)h * 64) + i) * 64 + j];
  float m = s;
  #pragma unroll
  for (int off = 32; off; off >>= 1) m = fmaxf(m, __shfl_xor(m, off));
  float e = __expf(s - m);
  float sum = e;
  #pragma unroll
  for (int off = 32; off; off >>= 1) sum += __shfl_xor(sum, off);
  attn[o] = e / sum;
}

// ---------------- K5 (MFMA): otok[i,d] = sum_j attn[i,j] * V[j,d]
__global__ __launch_bounds__(256) void k5_av(
    const bf16* __restrict__ tok, const float* __restrict__ attn, bf16* __restrict__ otok){
  __shared__ short vt[4][64 * 72];
  int t = threadIdx.x;
  int lane = t & 63, w = t >> 6;
  int r16 = lane & 15, g4 = lane >> 4;
  u32 bid = blockIdx.x;
  u32 q = bid & 3u, h = (bid >> 2) & 7u, b = bid >> 5;
  const bf16* vb = tok + ((size_t)(((2 * 16 + b) * 8 + h) * 64)) * 8192;
  const float* ab = attn + (((size_t)b * 8 + h) * 64) * 64;
  bf16* ob = otok + (((size_t)b * 8 + h) * 64) * 8192;

  bf16x8 af[4][2];
  #pragma unroll
  for (int it = 0; it < 4; it++)
    #pragma unroll
    for (int kt = 0; kt < 2; kt++){
      const float* ar = ab + (it * 16 + r16) * 64 + kt * 32 + g4 * 8;
      ABu pk;
      #pragma unroll
      for (int j = 0; j < 4; j++)
        pk.u[j] = f2bbits(ar[2 * j]) | (f2bbits(ar[2 * j + 1]) << 16);
      af[it][kt] = pk.v;
    }

  short* vtw = vt[w];
  for (int s = 0; s < 8; s++){
    int d0 = (int)q * 2048 + s * 256 + w * 64;
    uint4 ld[8];
    const bf16* vp = vb + (size_t)lane * 8192 + d0;
    #pragma unroll
    for (int u = 0; u < 8; u++) ld[u] = *(const uint4*)(vp + u * 8);
    #pragma unroll
    for (int u = 0; u < 8; u++){
      const u32* wd = (const u32*)&ld[u];
      #pragma unroll
      for (int e = 0; e < 4; e++){
        int d = u * 8 + e * 2;
        vtw[d * 72 + lane]       = (short)(wd[e] & 0xffffu);
        vtw[(d + 1) * 72 + lane] = (short)(wd[e] >> 16);
      }
    }
    #pragma unroll
    for (int dt = 0; dt < 4; dt++){
      bf16x8 b0 = *(const bf16x8*)&vtw[(dt * 16 + r16) * 72 + 0 * 32 + g4 * 8];
      bf16x8 b1 = *(const bf16x8*)&vtw[(dt * 16 + r16) * 72 + 1 * 32 + g4 * 8];
      #pragma unroll
      for (int it = 0; it < 4; it++){
        f32x4 acc = (f32x4){0.f,0.f,0.f,0.f};
        acc = __builtin_amdgcn_mfma_f32_16x16x32_bf16(af[it][0], b0, acc, 0, 0, 0);
        acc = __builtin_amdgcn_mfma_f32_16x16x32_bf16(af[it][1], b1, acc, 0, 0, 0);
        #pragma unroll
        for (int r = 0; r < 4; r++)
          ob[(size_t)(it * 16 + g4 * 4 + r) * 8192 + d0 + dt * 16 + r16] = f2b(acc[r]);
      }
    }
  }
}

// ---------------- K6 (MFMA): out[b,64,HW] fp32 = Wp[64,64] x OT[64,HW] + bias
__global__ __launch_bounds__(256) void k6_mfma(
    const bf16* __restrict__ otok, const float* __restrict__ wp,
    const float* __restrict__ bp, float* __restrict__ out){
  __shared__ uint4 xs[1024];
  int t = threadIdx.x;
  int lane = t & 63, w = t >> 6;
  u32 pix0 = blockIdx.x * 128u;
  u32 b = pix0 >> 16, hw0 = pix0 & 65535u;
  int y = (int)(hw0 >> 8);
  int p0 = y & 31, h = p0 >> 2, prow = (p0 & 3) * 2048;
  int iy = (y >> 5) << 3;

  {
    int pix = t & 127, half = t >> 7;
    int xx = (int)(hw0 & 255u) + pix;
    int i = iy + (xx >> 5), p1 = xx & 31;
    const bf16* ip = otok + ((((size_t)b * 8 + h) * 64 + i)) * 8192 + prow + p1 * 64;
    #pragma unroll
    for (int g = 0; g < 4; g++){
      int c8 = half * 4 + g;
      xs[c8 * 128 + pix] = *(const uint4*)(ip + c8 * 8);
    }
  }

  int r16 = lane & 15, g4 = lane >> 4;
  bf16x8 af[2];
  int och = w * 16 + r16;
  #pragma unroll
  for (int kt = 0; kt < 2; kt++){
    const float* wr = wp + och * 64 + kt * 32 + g4 * 8;
    ABu pk;
    #pragma unroll
    for (int j = 0; j < 4; j++)
      pk.u[j] = f2bbits(wr[2 * j]) | (f2bbits(wr[2 * j + 1]) << 16);
    af[kt] = pk.v;
  }
  float bias[4];
  #pragma unroll
  for (int r = 0; r < 4; r++) bias[r] = bp[w * 16 + g4 * 4 + r];
  __syncthreads();

  f32x4 acc[8];
  #pragma unroll
  for (int pt = 0; pt < 8; pt++) acc[pt] = (f32x4){bias[0], bias[1], bias[2], bias[3]};

  #pragma unroll
  for (int pt = 0; pt < 8; pt++){
    uint4 u0 = xs[(0 * 4 + g4) * 128 + pt * 16 + r16];
    uint4 u1 = xs[(1 * 4 + g4) * 128 + pt * 16 + r16];
    bf16x8 b0 = *reinterpret_cast<bf16x8*>(&u0);
    bf16x8 b1 = *reinterpret_cast<bf16x8*>(&u1);
    acc[pt] = __builtin_amdgcn_mfma_f32_16x16x32_bf16(af[0], b0, acc[pt], 0, 0, 0);
    acc[pt] = __builtin_amdgcn_mfma_f32_16x16x32_bf16(af[1], b1, acc[pt], 0, 0, 0);
  }

  float* op = out + (size_t)b * 64 * HWSZ + hw0;
  int ochb = w * 16 + g4 * 4;
  #pragma unroll
  for (int pt = 0; pt < 8; pt++)
    #pragma unroll
    for (int r = 0; r < 4; r++)
      op[(size_t)(ochb + r) * HWSZ + pt * 16 + r16] = acc[pt][r];
}

extern "C" void kernel_launch(void* const* d_in, const int* in_sizes, int n_in,
                              void* d_out, int out_size, void* d_ws, size_t ws_size,
                              hipStream_t stream){
  const float* x   = (const float*)d_in[0];
  const float* wq  = (const float*)d_in[1];
  const float* wdw = (const float*)d_in[2];
  const float* wp  = (const float*)d_in[3];
  const float* bp  = (const float*)d_in[4];
  const float* pos = (const float*)d_in[5];
  float* out = (float*)d_out;
  (void)in_sizes; (void)n_in; (void)out_size; (void)ws_size;

  char* ws = (char*)d_ws;
  bf16*  tok  = (bf16*)(ws + 402653184u);
  bf16*  otok = (bf16*)ws;
  float* sim4 = (float*)(ws + 134217728u);
  float* attn = (float*)(ws + 142606336u);

  k12_fused<<<dim3(8192), dim3(512), 0, stream>>>(x, wq, wdw, tok);
  k3_sim<<<dim3(512),   dim3(256), 0, stream>>>(tok, sim4);
  k4_softmax<<<dim3(8192), dim3(64), 0, stream>>>(sim4, pos, attn);
  k5_av<<<dim3(512),  dim3(256), 0, stream>>>(tok, attn, otok);
  k6_mfma<<<dim3(8192), dim3(256), 0, stream>>>(otok, wp, bp, out);
}